// Round 3
// baseline (702.929 us; speedup 1.0000x reference)
//
#include <hip/hip_runtime.h>
#include <hip/hip_bf16.h>
#include <math.h>
#include <string.h>

#define B_    2
#define C_    1536
#define S_    16384
#define H_    768
#define T_    367
#define P_    128
#define HALF_ 384
#define TT_   734                 // 2*T
#define PRED_ELEMS 24051712      // B*P*P*2T

// ws layout (float offsets)
#define XC_OFF 0                 // [B][4][P][C]   1,572,864 floats
#define XH_OFF 1572864           // [B][4][P][H]     786,432 floats
#define CS_OFF 2359296           // [B][4][P][HALF] float2  786,432 floats
#define INVF_OFF 3145728         // 384 doubles (768 float slots)

typedef short short8 __attribute__((ext_vector_type(8)));
typedef float f32x4  __attribute__((ext_vector_type(4)));

// ---------------- A0: gather embedding columns ----------------
__global__ void gather_cols(const float* __restrict__ emb,
                            const int* __restrict__ sp,
                            float* __restrict__ xc) {
    int blk = blockIdx.x;           // B*4*P = 1024
    int p = blk & 127;
    int g = (blk >> 7) & 3;
    int b = blk >> 9;
    int s = sp[(b * 4 + g) * P_ + p];
    const float* src = emb + (size_t)b * C_ * S_ + s;
    float* dst = xc + ((size_t)(b * 4 + g) * P_ + p) * C_;
    for (int c = threadIdx.x; c < C_; c += blockDim.x)
        dst[c] = src[(size_t)c * S_];
}

// ---------------- A1: gathered-logits GEMM + bias ----------------
__global__ __launch_bounds__(256) void small_gemm(const float* __restrict__ xc,
                                                  const float* __restrict__ w,
                                                  const float* __restrict__ bias,
                                                  const int* __restrict__ org,
                                                  float* __restrict__ xh) {
    __shared__ float Xs[64][33];
    __shared__ float Ws[64][33];
    int b = blockIdx.x, rt = blockIdx.y, ht = blockIdx.z;
    int o = org[b];
    int row0 = b * 512 + rt * 64;
    int h0 = ht * 64;
    int tid = threadIdx.x;
    int tx = tid & 15, ty = tid >> 4;
    float acc[4][4] = {};
    for (int k0 = 0; k0 < C_; k0 += 32) {
        for (int e = tid; e < 64 * 32; e += 256) {
            int i = e >> 5, k = e & 31;
            Xs[i][k] = xc[(size_t)(row0 + i) * C_ + k0 + k];
            Ws[i][k] = w[((size_t)o * H_ + h0 + i) * C_ + k0 + k];
        }
        __syncthreads();
        for (int k = 0; k < 32; ++k) {
            float a_[4], b_[4];
            #pragma unroll
            for (int u = 0; u < 4; ++u) a_[u] = Xs[ty * 4 + u][k];
            #pragma unroll
            for (int v = 0; v < 4; ++v) b_[v] = Ws[tx * 4 + v][k];
            #pragma unroll
            for (int u = 0; u < 4; ++u)
                #pragma unroll
                for (int v = 0; v < 4; ++v) acc[u][v] += a_[u] * b_[v];
        }
        __syncthreads();
    }
    for (int u = 0; u < 4; ++u)
        for (int v = 0; v < 4; ++v) {
            int r = row0 + ty * 4 + u, h = h0 + tx * 4 + v;
            xh[(size_t)r * H_ + h] = acc[u][v] + bias[o * H_ + h];
        }
}

// ---------------- A2a: inv-freq table (fp64, 384 elems, one tiny block) ----------------
__global__ void init_invf(double* __restrict__ invf) {
    int j = threadIdx.x;
    if (j < HALF_) invf[j] = exp2(-20.0 * (double)j / 384.0);
}

// ---------------- A2b: RoPE cos/sin table (fp64 reduce + HW sincos) ----------------
__global__ void rope_table(const int* __restrict__ sp,
                           const double* __restrict__ invf,
                           float2* __restrict__ cs) {
    int e = blockIdx.x * blockDim.x + threadIdx.x;  // B*4*P*HALF = 393216
    if (e >= B_ * 4 * P_ * HALF_) return;
    int j = e % HALF_;
    int r = e / HALF_;                               // (b*4+g)*P + p
    int s = sp[r];
    const double TWO_PI = 6.283185307179586476925286766559;
    double ang = (double)s * invf[j];
    double k = rint(ang * (1.0 / TWO_PI));
    float fr = (float)(ang - k * TWO_PI);            // exact to ~1e-13
    float sv, cv;
    __sincosf(fr, &sv, &cv);
    cs[e] = make_float2(cv, sv);
}

// ---------------- B: junction GEMM via bf16 MFMA ----------------
// block = one (b, sign, t); 4 waves, each 64x64 of the 128x128 output.
// K=768 as 12 chunks of 64 k (32 rope pairs). Tiles bf16 in LDS, stride 64
// ushorts (128B rows), XOR swizzle on 16B granules: gran' = gran ^ (row&7).
__global__ __launch_bounds__(256, 4) void junction_mfma(
    const float* __restrict__ xh, const float2* __restrict__ cs,
    const float* __restrict__ rpd, const float* __restrict__ rpa,
    const float* __restrict__ rnd, const float* __restrict__ rna,
    const int* __restrict__ org, const int* __restrict__ sp,
    __hip_bfloat16* __restrict__ w1) {
    __shared__ unsigned short tD[P_ * 64];   // 16KB
    __shared__ unsigned short tA[P_ * 64];   // 16KB
    __shared__ int vD[P_], vA[P_];

    // bijective XCD swizzle (nwg = 1468, nwg%8 = 4)
    int nwg = gridDim.x;
    int orig = blockIdx.x;
    int xcd = orig & 7;
    int q = nwg >> 3, r8 = nwg & 7;
    int blk = (xcd < r8 ? xcd * (q + 1) : r8 * (q + 1) + (xcd - r8) * q) + (orig >> 3);

    int t = blk % T_;
    int sign = (blk / T_) & 1;
    int b = blk / (2 * T_);
    int o = org[b];
    int gd = sign * 2, ga = sign * 2 + 1;
    const float* pd = sign ? rnd : rpd;
    const float* pa = sign ? rna : rpa;
    int tid = threadIdx.x;

    const float* sc_d = pd + ((size_t)(o * 2 + 0) * T_ + t) * H_;
    const float* of_d = pd + ((size_t)(o * 2 + 1) * T_ + t) * H_;
    const float* sc_a = pa + ((size_t)(o * 2 + 0) * T_ + t) * H_;
    const float* of_a = pa + ((size_t)(o * 2 + 1) * T_ + t) * H_;

    if (tid < P_) {
        vD[tid] = sp[(b * 4 + gd) * P_ + tid] >= 0;
        vA[tid] = sp[(b * 4 + ga) * P_ + tid] >= 0;
    }
    const float*  xd = xh + ((size_t)(b * 4 + gd) * P_) * H_;
    const float*  xa = xh + ((size_t)(b * 4 + ga) * P_) * H_;
    const float2* cd = cs + ((size_t)(b * 4 + gd) * P_) * HALF_;
    const float2* ca = cs + ((size_t)(b * 4 + ga) * P_) * HALF_;

    int lane = tid & 63, wid = tid >> 6;
    int wrow = (wid >> 1) * 64, wcol = (wid & 1) * 64;
    int lr = lane & 15, lq = lane >> 4;

    f32x4 acc[4][4];
    #pragma unroll
    for (int i = 0; i < 4; ++i)
        #pragma unroll
        for (int j = 0; j < 4; ++j)
            acc[i][j] = (f32x4){0.f, 0.f, 0.f, 0.f};

    int jp = tid & 15;        // handles j-pairs {j0+2jp, j0+2jp+1}
    int prow = tid >> 4;      // 0..15; pass p = pass*16 + prow
    // swizzled ds_write target (ushort idx within row): gran = jp>>1
    // frag-read granule xor term, hoisted: depends only on lq, lr
    int gr0 = (lq ^ (lr & 7)) * 8;       // kk=0  -> granule lq ^ (row&7)
    // kk=32 -> granule (4+lq) ^ (row&7) = (lq^(row&7)) ^ 4 -> idx ^ 32

    for (int ch = 0; ch < 12; ++ch) {
        int jb = ch * 32 + 2 * jp;
        // per-chunk affine coefs (registers; same-address lanes broadcast via L1)
        float2 s1d = *(const float2*)&sc_d[jb];
        float2 o1d = *(const float2*)&of_d[jb];
        float2 s2d = *(const float2*)&sc_d[jb + HALF_];
        float2 o2d = *(const float2*)&of_d[jb + HALF_];
        float2 s1a = *(const float2*)&sc_a[jb];
        float2 o1a = *(const float2*)&of_a[jb];
        float2 s2a = *(const float2*)&sc_a[jb + HALF_];
        float2 o2a = *(const float2*)&of_a[jb + HALF_];

        if (ch) __syncthreads();   // previous chunk's MFMA reads done

        #pragma unroll 2
        for (int pass = 0; pass < 8; ++pass) {
            int p = pass * 16 + prow;
            int sw = p * 64 + (((jp >> 1) ^ (p & 7)) << 3) + ((jp & 1) << 2);
            // ---- donor ----
            {
                float2 x1 = *(const float2*)&xd[p * H_ + jb];
                float2 x2 = *(const float2*)&xd[p * H_ + jb + HALF_];
                float4 cv = *(const float4*)&cd[p * HALF_ + jb]; // c0,s0,c1,s1
                float u1 = fmaf(s1d.x, x1.x, o1d.x);
                float u2 = fmaf(s2d.x, x2.x, o2d.x);
                float r1 = u1 * cv.x - u2 * cv.y;
                float r2 = u1 * cv.y + u2 * cv.x;
                float v1 = fmaf(s1d.y, x1.y, o1d.y);
                float v2 = fmaf(s2d.y, x2.y, o2d.y);
                float r3 = v1 * cv.z - v2 * cv.w;
                float r4 = v1 * cv.w + v2 * cv.z;
                union { unsigned short us[4]; uint2 u2v; } pk;
                __hip_bfloat16 h0 = __float2bfloat16(r1);
                __hip_bfloat16 h1 = __float2bfloat16(r2);
                __hip_bfloat16 h2 = __float2bfloat16(r3);
                __hip_bfloat16 h3 = __float2bfloat16(r4);
                __builtin_memcpy(&pk.us[0], &h0, 2);
                __builtin_memcpy(&pk.us[1], &h1, 2);
                __builtin_memcpy(&pk.us[2], &h2, 2);
                __builtin_memcpy(&pk.us[3], &h3, 2);
                *(uint2*)&tD[sw] = pk.u2v;
            }
            // ---- acceptor ----
            {
                float2 x1 = *(const float2*)&xa[p * H_ + jb];
                float2 x2 = *(const float2*)&xa[p * H_ + jb + HALF_];
                float4 cv = *(const float4*)&ca[p * HALF_ + jb];
                float u1 = fmaf(s1a.x, x1.x, o1a.x);
                float u2 = fmaf(s2a.x, x2.x, o2a.x);
                float r1 = u1 * cv.x - u2 * cv.y;
                float r2 = u1 * cv.y + u2 * cv.x;
                float v1 = fmaf(s1a.y, x1.y, o1a.y);
                float v2 = fmaf(s2a.y, x2.y, o2a.y);
                float r3 = v1 * cv.z - v2 * cv.w;
                float r4 = v1 * cv.w + v2 * cv.z;
                union { unsigned short us[4]; uint2 u2v; } pk;
                __hip_bfloat16 h0 = __float2bfloat16(r1);
                __hip_bfloat16 h1 = __float2bfloat16(r2);
                __hip_bfloat16 h2 = __float2bfloat16(r3);
                __hip_bfloat16 h3 = __float2bfloat16(r4);
                __builtin_memcpy(&pk.us[0], &h0, 2);
                __builtin_memcpy(&pk.us[1], &h1, 2);
                __builtin_memcpy(&pk.us[2], &h2, 2);
                __builtin_memcpy(&pk.us[3], &h3, 2);
                *(uint2*)&tA[sw] = pk.u2v;
            }
        }
        __syncthreads();

        __builtin_amdgcn_s_setprio(1);
        #pragma unroll
        for (int kk = 0; kk < 64; kk += 32) {
            short8 af[4], bfr[4];
            #pragma unroll
            for (int fi = 0; fi < 4; ++fi) {
                int row = wrow + fi * 16 + lr;
                af[fi] = *(const short8*)&tD[row * 64 + (gr0 ^ (kk))];
            }
            #pragma unroll
            for (int fj = 0; fj < 4; ++fj) {
                int row = wcol + fj * 16 + lr;
                bfr[fj] = *(const short8*)&tA[row * 64 + (gr0 ^ (kk))];
            }
            #pragma unroll
            for (int fi = 0; fi < 4; ++fi)
                #pragma unroll
                for (int fj = 0; fj < 4; ++fj)
                    acc[fi][fj] = __builtin_amdgcn_mfma_f32_16x16x32_bf16(
                        af[fi], bfr[fj], acc[fi][fj], 0, 0, 0);
        }
        __builtin_amdgcn_s_setprio(0);
    }

    // ---- epilogue: softplus + mask, staged bf16 [b][sign][t][d][a] ----
    __hip_bfloat16* dst = w1 + (((size_t)(b * 2 + sign) * T_ + t) * P_) * P_;
    #pragma unroll
    for (int fi = 0; fi < 4; ++fi) {
        #pragma unroll
        for (int rr = 0; rr < 4; ++rr) {
            int d = wrow + fi * 16 + lq * 4 + rr;
            int vd = vD[d];
            #pragma unroll
            for (int fj = 0; fj < 4; ++fj) {
                int a = wcol + fj * 16 + lr;
                float x = acc[fi][fj][rr];
                float v = 0.0f;
                if (vd && vA[a]) v = (x > 15.0f) ? x : log1pf(expf(x));
                dst[d * P_ + a] = __float2bfloat16(v);
            }
        }
    }
}

// ---------------- C: transpose bf16 [b][sign][t][d][a] -> f32 [b][d][a][sign*T+t] ----------------
__global__ __launch_bounds__(256) void transpose_out(const __hip_bfloat16* __restrict__ w1,
                                                     float* __restrict__ pred) {
    __shared__ float tile[64 * 129];
    int blk = blockIdx.x;            // bs*128*6 + d*6 + tt   (3072 blocks)
    int tt = blk % 6;
    int d = (blk / 6) % P_;
    int bs = blk / (6 * P_);         // b*2+sign
    int b = bs >> 1, sign = bs & 1;
    int t0 = tt * 64;
    int tcnt = min(64, T_ - t0);
    int tid = threadIdx.x;

    const __hip_bfloat16* src = w1 + (size_t)bs * T_ * P_ * P_ + (size_t)d * P_;
    for (int e = tid; e < tcnt * P_; e += 256) {
        int i = e >> 7, a = e & 127;
        tile[i * 129 + a] = __bfloat162float(src[(size_t)(t0 + i) * P_ * P_ + a]);
    }
    __syncthreads();
    float* dst = pred + ((size_t)(b * P_ + d) * P_) * TT_ + sign * T_ + t0;
    for (int e = tid; e < P_ * 64; e += 256) {
        int a = e >> 6, ii = e & 63;
        if (ii < tcnt) dst[(size_t)a * TT_ + ii] = tile[ii * 129 + a];
    }
}

// ---------------- D: mask fill ----------------
__global__ void mask_fill(const int* __restrict__ sp, float* __restrict__ mask) {
    int blk = blockIdx.x;            // (b*128+d)*128+a   (32768 blocks)
    int a = blk & 127;
    int d = (blk >> 7) & 127;
    int b = blk >> 14;
    bool vp = (sp[(b * 4 + 0) * P_ + d] >= 0) && (sp[(b * 4 + 1) * P_ + a] >= 0);
    bool vn = (sp[(b * 4 + 2) * P_ + d] >= 0) && (sp[(b * 4 + 3) * P_ + a] >= 0);
    float* dst = mask + (size_t)blk * TT_;
    for (int st = threadIdx.x; st < TT_; st += blockDim.x)
        dst[st] = (st < T_ ? vp : vn) ? 1.0f : 0.0f;
}

extern "C" void kernel_launch(void* const* d_in, const int* in_sizes, int n_in,
                              void* d_out, int out_size, void* d_ws, size_t ws_size,
                              hipStream_t stream) {
    const float* emb  = (const float*)d_in[0];
    const float* w    = (const float*)d_in[1];
    const float* bias = (const float*)d_in[2];
    const float* rpd  = (const float*)d_in[3];
    const float* rpa  = (const float*)d_in[4];
    const float* rnd  = (const float*)d_in[5];
    const float* rna  = (const float*)d_in[6];
    const int*   org  = (const int*)d_in[7];
    const int*   sp   = (const int*)d_in[8];

    float* out = (float*)d_out;
    float* ws  = (float*)d_ws;
    float* xc  = ws + XC_OFF;
    float* xh  = ws + XH_OFF;
    float2* cs = (float2*)(ws + CS_OFF);
    double* invf = (double*)(ws + INVF_OFF);
    float* pred  = out;
    float* maskp = out + PRED_ELEMS;
    __hip_bfloat16* w1 = (__hip_bfloat16*)maskp;   // bf16 staging in mask half

    init_invf<<<1, 384, 0, stream>>>(invf);
    gather_cols<<<1024, 256, 0, stream>>>(emb, sp, xc);
    dim3 g1(2, 8, 12);
    small_gemm<<<g1, 256, 0, stream>>>(xc, w, bias, org, xh);
    rope_table<<<1536, 256, 0, stream>>>(sp, invf, cs);
    junction_mfma<<<2 * 2 * T_, 256, 0, stream>>>(xh, cs, rpd, rpa, rnd, rna, org, sp, w1);
    transpose_out<<<2 * 2 * P_ * 6, 256, 0, stream>>>(w1, pred);
    mask_fill<<<32768, 256, 0, stream>>>(sp, maskp);
}

// Round 4
// 600.626 us; speedup vs baseline: 1.1703x; 1.1703x over previous
//
#include <hip/hip_runtime.h>
#include <hip/hip_bf16.h>
#include <math.h>
#include <string.h>

#define B_    2
#define C_    1536
#define S_    16384
#define H_    768
#define T_    367
#define P_    128
#define HALF_ 384
#define TT_   734                 // 2*T
#define PRED_ELEMS 24051712      // B*P*P*2T

// ws layout (float slots)
#define XC_OFF   0               // [B][4][P][C] f32      1,572,864 floats
#define XHB_OFF  1572864         // [B][4][P][H] bf16     786,432 ushorts (393,216 slots)
#define CSB_OFF  1966080         // [B][4][P][HALF] bf16x2 393,216 uints
#define INVF_OFF 2359296         // 384 doubles

typedef short short8 __attribute__((ext_vector_type(8)));
typedef float f32x4  __attribute__((ext_vector_type(4)));

__device__ __forceinline__ float bflo(unsigned int u) { return __uint_as_float(u << 16); }
__device__ __forceinline__ float bfhi(unsigned int u) { return __uint_as_float(u & 0xffff0000u); }
__device__ __forceinline__ unsigned int packbf2(float a, float b) {
    __hip_bfloat162 h = __float22bfloat162_rn(make_float2(a, b));
    unsigned int r; __builtin_memcpy(&r, &h, 4); return r;
}
__device__ __forceinline__ unsigned short packbf1(float a) {
    __hip_bfloat16 h = __float2bfloat16(a);
    unsigned short r; __builtin_memcpy(&r, &h, 2); return r;
}

// ---------------- A0: gather embedding columns ----------------
__global__ void gather_cols(const float* __restrict__ emb,
                            const int* __restrict__ sp,
                            float* __restrict__ xc) {
    int blk = blockIdx.x;           // B*4*P = 1024
    int p = blk & 127;
    int g = (blk >> 7) & 3;
    int b = blk >> 9;
    int s = sp[(b * 4 + g) * P_ + p];
    const float* src = emb + (size_t)b * C_ * S_ + s;
    float* dst = xc + ((size_t)(b * 4 + g) * P_ + p) * C_;
    for (int c = threadIdx.x; c < C_; c += blockDim.x)
        dst[c] = src[(size_t)c * S_];
}

// ---------------- A1: gathered-logits GEMM + bias (fp32, bf16 output) ----------------
__global__ __launch_bounds__(256) void small_gemm(const float* __restrict__ xc,
                                                  const float* __restrict__ w,
                                                  const float* __restrict__ bias,
                                                  const int* __restrict__ org,
                                                  unsigned short* __restrict__ xhb) {
    __shared__ float Xs[64][33];
    __shared__ float Ws[64][33];
    int b = blockIdx.x, rt = blockIdx.y, ht = blockIdx.z;
    int o = org[b];
    int row0 = b * 512 + rt * 64;
    int h0 = ht * 64;
    int tid = threadIdx.x;
    int tx = tid & 15, ty = tid >> 4;
    float acc[4][4] = {};
    for (int k0 = 0; k0 < C_; k0 += 32) {
        for (int e = tid; e < 64 * 32; e += 256) {
            int i = e >> 5, k = e & 31;
            Xs[i][k] = xc[(size_t)(row0 + i) * C_ + k0 + k];
            Ws[i][k] = w[((size_t)o * H_ + h0 + i) * C_ + k0 + k];
        }
        __syncthreads();
        for (int k = 0; k < 32; ++k) {
            float a_[4], b_[4];
            #pragma unroll
            for (int u = 0; u < 4; ++u) a_[u] = Xs[ty * 4 + u][k];
            #pragma unroll
            for (int v = 0; v < 4; ++v) b_[v] = Ws[tx * 4 + v][k];
            #pragma unroll
            for (int u = 0; u < 4; ++u)
                #pragma unroll
                for (int v = 0; v < 4; ++v) acc[u][v] += a_[u] * b_[v];
        }
        __syncthreads();
    }
    for (int u = 0; u < 4; ++u)
        for (int v = 0; v < 4; ++v) {
            int r = row0 + ty * 4 + u, h = h0 + tx * 4 + v;
            xhb[(size_t)r * H_ + h] = packbf1(acc[u][v] + bias[o * H_ + h]);
        }
}

// ---------------- A2a: inv-freq table (fp64) ----------------
__global__ void init_invf(double* __restrict__ invf) {
    int j = threadIdx.x;
    if (j < HALF_) invf[j] = exp2(-20.0 * (double)j / 384.0);
}

// ---------------- A2b: RoPE cos/sin table -> packed bf16 (cos|sin) ----------------
__global__ void rope_table(const int* __restrict__ sp,
                           const double* __restrict__ invf,
                           unsigned int* __restrict__ cs) {
    int e = blockIdx.x * blockDim.x + threadIdx.x;  // B*4*P*HALF = 393216
    if (e >= B_ * 4 * P_ * HALF_) return;
    int j = e % HALF_;
    int r = e / HALF_;
    int s = sp[r];
    const double TWO_PI = 6.283185307179586476925286766559;
    double ang = (double)s * invf[j];
    double k = rint(ang * (1.0 / TWO_PI));
    float fr = (float)(ang - k * TWO_PI);
    float sv, cv;
    __sincosf(fr, &sv, &cv);
    cs[e] = packbf2(cv, sv);
}

// ---------------- B: junction GEMM via bf16 MFMA ----------------
// block = one (b, sign, t); 4 waves, each 64x64 of the 128x128 output.
// K=768 as 12 chunks of 64 k (32 rope pairs). All per-chunk global data
// (bf16 x, bf16 cos/sin, f32 coefs) loaded batched into registers at chunk
// top; tiles built in swizzled bf16 LDS; coalesced LDS-staged epilogue.
__global__ __launch_bounds__(256, 3) void junction_mfma(
    const unsigned short* __restrict__ xhb, const unsigned int* __restrict__ csb,
    const float* __restrict__ rpd, const float* __restrict__ rpa,
    const float* __restrict__ rnd, const float* __restrict__ rna,
    const int* __restrict__ org, const int* __restrict__ sp,
    unsigned short* __restrict__ w1) {
    __shared__ __align__(16) unsigned short smem[2 * P_ * 64];   // tD | tA, 32KB
    __shared__ int vD[P_], vA[P_];
    unsigned short* tD = smem;
    unsigned short* tA = smem + P_ * 64;

    // bijective XCD swizzle (nwg = 1468, nwg%8 = 4)
    int nwg = gridDim.x;
    int orig = blockIdx.x;
    int xcd = orig & 7;
    int q = nwg >> 3, r8 = nwg & 7;
    int blk = (xcd < r8 ? xcd * (q + 1) : r8 * (q + 1) + (xcd - r8) * q) + (orig >> 3);

    int t = blk % T_;
    int sign = (blk / T_) & 1;
    int b = blk / (2 * T_);
    int o = org[b];
    int gd = sign * 2, ga = sign * 2 + 1;
    const float* pd = sign ? rnd : rpd;
    const float* pa = sign ? rna : rpa;
    int tid = threadIdx.x;

    const float* sc_d = pd + ((size_t)(o * 2 + 0) * T_ + t) * H_;
    const float* of_d = pd + ((size_t)(o * 2 + 1) * T_ + t) * H_;
    const float* sc_a = pa + ((size_t)(o * 2 + 0) * T_ + t) * H_;
    const float* of_a = pa + ((size_t)(o * 2 + 1) * T_ + t) * H_;

    if (tid < P_) {
        vD[tid] = sp[(b * 4 + gd) * P_ + tid] >= 0;
        vA[tid] = sp[(b * 4 + ga) * P_ + tid] >= 0;
    }
    const unsigned short* xh_d = xhb + ((size_t)(b * 4 + gd) * P_) * H_;
    const unsigned short* xh_a = xhb + ((size_t)(b * 4 + ga) * P_) * H_;
    const unsigned int*   cs_d = csb + ((size_t)(b * 4 + gd) * P_) * HALF_;
    const unsigned int*   cs_a = csb + ((size_t)(b * 4 + ga) * P_) * HALF_;

    int lane = tid & 63, wid = tid >> 6;
    int wrow = (wid >> 1) * 64, wcol = (wid & 1) * 64;
    int lr = lane & 15, lq = lane >> 4;

    f32x4 acc[4][4];
    #pragma unroll
    for (int i = 0; i < 4; ++i)
        #pragma unroll
        for (int j = 0; j < 4; ++j)
            acc[i][j] = (f32x4){0.f, 0.f, 0.f, 0.f};

    int jp = tid & 15;        // j-pair pair {2jp, 2jp+1} within chunk
    int prow = tid >> 4;      // 0..15
    int gr0 = (lq ^ (lr & 7)) * 8;   // MFMA read granule swizzle (kk=32 -> ^32)

    for (int ch = 0; ch < 12; ++ch) {
        int jb = ch * 32 + 2 * jp;
        // ---- batched loads: everything this chunk needs, issued up front ----
        unsigned int xd1[8], xd2[8], xa1[8], xa2[8];
        uint2 cdw[8], caw[8];
        #pragma unroll
        for (int ps = 0; ps < 8; ++ps) {
            int p = ps * 16 + prow;
            const unsigned short* xdp = xh_d + p * H_ + jb;
            xd1[ps] = *(const unsigned int*)xdp;
            xd2[ps] = *(const unsigned int*)(xdp + HALF_);
            cdw[ps] = *(const uint2*)(cs_d + p * HALF_ + jb);
            const unsigned short* xap = xh_a + p * H_ + jb;
            xa1[ps] = *(const unsigned int*)xap;
            xa2[ps] = *(const unsigned int*)(xap + HALF_);
            caw[ps] = *(const uint2*)(cs_a + p * HALF_ + jb);
        }
        float2 s1d = *(const float2*)(sc_d + jb);
        float2 o1d = *(const float2*)(of_d + jb);
        float2 s2d = *(const float2*)(sc_d + jb + HALF_);
        float2 o2d = *(const float2*)(of_d + jb + HALF_);
        float2 s1a = *(const float2*)(sc_a + jb);
        float2 o1a = *(const float2*)(of_a + jb);
        float2 s2a = *(const float2*)(sc_a + jb + HALF_);
        float2 o2a = *(const float2*)(of_a + jb + HALF_);

        if (ch) __syncthreads();   // previous chunk's MFMA reads done (drains loads too)

        // ---- build tiles (register-only inputs) ----
        #pragma unroll
        for (int ps = 0; ps < 8; ++ps) {
            int p = ps * 16 + prow;
            int sw = p * 64 + (((jp >> 1) ^ (p & 7)) << 3) + ((jp & 1) << 2);
            {
                float x1l = bflo(xd1[ps]), x1h = bfhi(xd1[ps]);
                float x2l = bflo(xd2[ps]), x2h = bfhi(xd2[ps]);
                float c0 = bflo(cdw[ps].x), s0 = bfhi(cdw[ps].x);
                float c1 = bflo(cdw[ps].y), s1 = bfhi(cdw[ps].y);
                float u1 = fmaf(s1d.x, x1l, o1d.x);
                float u2 = fmaf(s2d.x, x2l, o2d.x);
                float v1 = fmaf(s1d.y, x1h, o1d.y);
                float v2 = fmaf(s2d.y, x2h, o2d.y);
                uint2 wv;
                wv.x = packbf2(u1 * c0 - u2 * s0, u1 * s0 + u2 * c0);
                wv.y = packbf2(v1 * c1 - v2 * s1, v1 * s1 + v2 * c1);
                *(uint2*)&tD[sw] = wv;
            }
            {
                float x1l = bflo(xa1[ps]), x1h = bfhi(xa1[ps]);
                float x2l = bflo(xa2[ps]), x2h = bfhi(xa2[ps]);
                float c0 = bflo(caw[ps].x), s0 = bfhi(caw[ps].x);
                float c1 = bflo(caw[ps].y), s1 = bfhi(caw[ps].y);
                float u1 = fmaf(s1a.x, x1l, o1a.x);
                float u2 = fmaf(s2a.x, x2l, o2a.x);
                float v1 = fmaf(s1a.y, x1h, o1a.y);
                float v2 = fmaf(s2a.y, x2h, o2a.y);
                uint2 wv;
                wv.x = packbf2(u1 * c0 - u2 * s0, u1 * s0 + u2 * c0);
                wv.y = packbf2(v1 * c1 - v2 * s1, v1 * s1 + v2 * c1);
                *(uint2*)&tA[sw] = wv;
            }
        }
        __syncthreads();

        __builtin_amdgcn_s_setprio(1);
        #pragma unroll
        for (int kk = 0; kk < 64; kk += 32) {
            short8 af[4], bfr[4];
            #pragma unroll
            for (int fi = 0; fi < 4; ++fi) {
                int row = wrow + fi * 16 + lr;
                af[fi] = *(const short8*)&tD[row * 64 + (gr0 ^ kk)];
            }
            #pragma unroll
            for (int fj = 0; fj < 4; ++fj) {
                int row = wcol + fj * 16 + lr;
                bfr[fj] = *(const short8*)&tA[row * 64 + (gr0 ^ kk)];
            }
            #pragma unroll
            for (int fi = 0; fi < 4; ++fi)
                #pragma unroll
                for (int fj = 0; fj < 4; ++fj)
                    acc[fi][fj] = __builtin_amdgcn_mfma_f32_16x16x32_bf16(
                        af[fi], bfr[fj], acc[fi][fj], 0, 0, 0);
        }
        __builtin_amdgcn_s_setprio(0);
    }

    // ---- epilogue: softplus+mask in regs -> bf16 LDS stage -> coalesced copy ----
    __syncthreads();              // tiles dead; reuse smem as 32KB stage
    #pragma unroll
    for (int fi = 0; fi < 4; ++fi) {
        #pragma unroll
        for (int rr = 0; rr < 4; ++rr) {
            int d = wrow + fi * 16 + lq * 4 + rr;
            int vd = vD[d];
            #pragma unroll
            for (int fj = 0; fj < 4; ++fj) {
                int a = wcol + fj * 16 + lr;
                float x = acc[fi][fj][rr];
                float v = 0.0f;
                if (vd && vA[a]) v = (x > 15.0f) ? x : log1pf(expf(x));
                smem[d * P_ + a] = packbf1(v);
            }
        }
    }
    __syncthreads();
    const uint4* src4 = (const uint4*)smem;                       // 2048 uint4
    uint4* dst4 = (uint4*)(w1 + ((size_t)((b * 2 + sign) * T_ + t) * P_) * P_);
    for (int i = tid; i < 2048; i += 256) dst4[i] = src4[i];
}

// ---------------- C: transpose bf16 [b][sign][t][d][a] -> f32 [b][d][a][sign*T+t] ----------------
__global__ __launch_bounds__(256) void transpose_out(const __hip_bfloat16* __restrict__ w1,
                                                     float* __restrict__ pred) {
    __shared__ float tile[64 * 129];
    int blk = blockIdx.x;            // bs*128*6 + d*6 + tt   (3072 blocks)
    int tt = blk % 6;
    int d = (blk / 6) % P_;
    int bs = blk / (6 * P_);         // b*2+sign
    int b = bs >> 1, sign = bs & 1;
    int t0 = tt * 64;
    int tcnt = min(64, T_ - t0);
    int tid = threadIdx.x;

    const __hip_bfloat16* src = w1 + (size_t)bs * T_ * P_ * P_ + (size_t)d * P_;
    for (int e = tid; e < tcnt * P_; e += 256) {
        int i = e >> 7, a = e & 127;
        tile[i * 129 + a] = __bfloat162float(src[(size_t)(t0 + i) * P_ * P_ + a]);
    }
    __syncthreads();
    float* dst = pred + ((size_t)(b * P_ + d) * P_) * TT_ + sign * T_ + t0;
    for (int e = tid; e < P_ * 64; e += 256) {
        int a = e >> 6, ii = e & 63;
        if (ii < tcnt) dst[(size_t)a * TT_ + ii] = tile[ii * 129 + a];
    }
}

// ---------------- D: mask fill ----------------
__global__ void mask_fill(const int* __restrict__ sp, float* __restrict__ mask) {
    int blk = blockIdx.x;            // (b*128+d)*128+a   (32768 blocks)
    int a = blk & 127;
    int d = (blk >> 7) & 127;
    int b = blk >> 14;
    bool vp = (sp[(b * 4 + 0) * P_ + d] >= 0) && (sp[(b * 4 + 1) * P_ + a] >= 0);
    bool vn = (sp[(b * 4 + 2) * P_ + d] >= 0) && (sp[(b * 4 + 3) * P_ + a] >= 0);
    float* dst = mask + (size_t)blk * TT_;
    for (int st = threadIdx.x; st < TT_; st += blockDim.x)
        dst[st] = (st < T_ ? vp : vn) ? 1.0f : 0.0f;
}

extern "C" void kernel_launch(void* const* d_in, const int* in_sizes, int n_in,
                              void* d_out, int out_size, void* d_ws, size_t ws_size,
                              hipStream_t stream) {
    const float* emb  = (const float*)d_in[0];
    const float* w    = (const float*)d_in[1];
    const float* bias = (const float*)d_in[2];
    const float* rpd  = (const float*)d_in[3];
    const float* rpa  = (const float*)d_in[4];
    const float* rnd  = (const float*)d_in[5];
    const float* rna  = (const float*)d_in[6];
    const int*   org  = (const int*)d_in[7];
    const int*   sp   = (const int*)d_in[8];

    float* out = (float*)d_out;
    float* ws  = (float*)d_ws;
    float* xc  = ws + XC_OFF;
    unsigned short* xhb = (unsigned short*)(ws + XHB_OFF);
    unsigned int*   csb = (unsigned int*)(ws + CSB_OFF);
    double* invf = (double*)(ws + INVF_OFF);
    float* pred  = out;
    float* maskp = out + PRED_ELEMS;
    unsigned short* w1 = (unsigned short*)maskp;   // bf16 staging in mask half

    init_invf<<<1, 384, 0, stream>>>(invf);
    gather_cols<<<1024, 256, 0, stream>>>(emb, sp, xc);
    dim3 g1(2, 8, 12);
    small_gemm<<<g1, 256, 0, stream>>>(xc, w, bias, org, xhb);
    rope_table<<<1536, 256, 0, stream>>>(sp, invf, csb);
    junction_mfma<<<2 * 2 * T_, 256, 0, stream>>>(xhb, csb, rpd, rpa, rnd, rna, org, sp, w1);
    transpose_out<<<2 * 2 * P_ * 6, 256, 0, stream>>>((const __hip_bfloat16*)w1, pred);
    mask_fill<<<32768, 256, 0, stream>>>(sp, maskp);
}

// Round 5
// 387.368 us; speedup vs baseline: 1.8146x; 1.5505x over previous
//
#include <hip/hip_runtime.h>
#include <hip/hip_bf16.h>
#include <math.h>
#include <string.h>

#define B_    2
#define C_    1536
#define S_    16384
#define H_    768
#define T_    367
#define P_    128
#define HALF_ 384
#define TT_   734                 // 2*T
#define PRED_ELEMS 24051712      // B*P*P*2T

// ws layout (float slots)
#define XH_OFF   0               // [B*4*P][H] f32        786,432
#define COS_OFF  786432          // [B*4*P][HALF] f32     393,216
#define SIN_OFF  1179648         // [B*4*P][HALF] f32     393,216
#define INVF_OFF 1572864         // 384 doubles            768
#define XCB_OFF  1573632         // [B*4*P][C] bf16       786,432 slots
// total ~9.44 MB

typedef short short8 __attribute__((ext_vector_type(8)));
typedef float f32x4  __attribute__((ext_vector_type(4)));
typedef float f32x2  __attribute__((ext_vector_type(2)));

__device__ __forceinline__ unsigned int packbf2(float a, float b) {
    __hip_bfloat162 h = __float22bfloat162_rn(make_float2(a, b));
    unsigned int r; __builtin_memcpy(&r, &h, 4); return r;
}
__device__ __forceinline__ unsigned short packbf1(float a) {
    __hip_bfloat16 h = __float2bfloat16(a);
    unsigned short r; __builtin_memcpy(&r, &h, 2); return r;
}

// ---------------- A0: gather embedding columns -> bf16 ----------------
__global__ void gather_cols(const float* __restrict__ emb,
                            const int* __restrict__ sp,
                            unsigned short* __restrict__ xcb) {
    int blk = blockIdx.x;           // B*4*P = 1024
    int p = blk & 127;
    int g = (blk >> 7) & 3;
    int b = blk >> 9;
    int s = sp[(b * 4 + g) * P_ + p];
    const float* src = emb + (size_t)b * C_ * S_ + s;
    unsigned short* dst = xcb + ((size_t)(b * 4 + g) * P_ + p) * C_;
    for (int c = threadIdx.x; c < C_; c += blockDim.x)
        dst[c] = packbf1(src[(size_t)c * S_]);
}

// ---------------- A1: gathered-logits GEMM via bf16 MFMA, f32 out ----------------
// M=1024 (rows r=(b*4+g)*128+p), N=768 (h), K=1536 (c). tile 128x64, 4 waves.
__global__ __launch_bounds__(256) void logits_mfma(
    const unsigned short* __restrict__ xcb, const float* __restrict__ w,
    const float* __restrict__ bias, const int* __restrict__ org,
    float* __restrict__ xh) {
    __shared__ __align__(16) unsigned short tX[128 * 64];  // 16KB
    __shared__ __align__(16) unsigned short tW[64 * 64];   // 8KB
    int mt = blockIdx.x;             // 0..7
    int nt = blockIdx.y;             // 0..11
    int o = org[mt >> 2];
    int r0 = mt * 128, h0 = nt * 64;
    int tid = threadIdx.x;
    int lane = tid & 63, wid = tid >> 6;
    int wrow = (wid >> 1) * 64, wcol = (wid & 1) * 32;
    int lr = lane & 15, lq = lane >> 4;
    int gr0 = (lq ^ (lr & 7)) * 8;

    f32x4 acc[4][2];
    #pragma unroll
    for (int i = 0; i < 4; ++i)
        #pragma unroll
        for (int j = 0; j < 2; ++j) acc[i][j] = (f32x4){0.f, 0.f, 0.f, 0.f};

    int xrow = tid >> 1, xhalf = tid & 1;       // X staging: 2 thr/row
    int wr = tid >> 2, wq = tid & 3;            // W staging: 4 thr/row

    for (int kc = 0; kc < C_; kc += 64) {
        if (kc) __syncthreads();
        {   // stage X (bf16 direct)
            const unsigned short* src = xcb + (size_t)(r0 + xrow) * C_ + kc + xhalf * 32;
            unsigned short* drow = tX + xrow * 64;
            #pragma unroll
            for (int i = 0; i < 4; ++i) {
                uint4 v = *(const uint4*)(src + i * 8);
                int g = xhalf * 4 + i;
                *(uint4*)&drow[(g ^ (xrow & 7)) * 8] = v;
            }
        }
        {   // stage W (f32 -> bf16)
            const float* srcw = w + ((size_t)o * H_ + h0 + wr) * C_ + kc + wq * 16;
            unsigned short* drow = tW + wr * 64;
            #pragma unroll
            for (int i = 0; i < 2; ++i) {
                float4 v0 = *(const float4*)(srcw + i * 8);
                float4 v1 = *(const float4*)(srcw + i * 8 + 4);
                uint4 pk;
                pk.x = packbf2(v0.x, v0.y); pk.y = packbf2(v0.z, v0.w);
                pk.z = packbf2(v1.x, v1.y); pk.w = packbf2(v1.z, v1.w);
                int g = wq * 2 + i;
                *(uint4*)&drow[(g ^ (wr & 7)) * 8] = pk;
            }
        }
        __syncthreads();
        #pragma unroll
        for (int kk = 0; kk < 64; kk += 32) {
            short8 af[4], bf2[2];
            #pragma unroll
            for (int fi = 0; fi < 4; ++fi)
                af[fi] = *(const short8*)&tX[(wrow + fi * 16 + lr) * 64 + (gr0 ^ kk)];
            #pragma unroll
            for (int fj = 0; fj < 2; ++fj)
                bf2[fj] = *(const short8*)&tW[(wcol + fj * 16 + lr) * 64 + (gr0 ^ kk)];
            #pragma unroll
            for (int fi = 0; fi < 4; ++fi)
                #pragma unroll
                for (int fj = 0; fj < 2; ++fj)
                    acc[fi][fj] = __builtin_amdgcn_mfma_f32_16x16x32_bf16(
                        af[fi], bf2[fj], acc[fi][fj], 0, 0, 0);
        }
    }
    #pragma unroll
    for (int fi = 0; fi < 4; ++fi)
        #pragma unroll
        for (int rr = 0; rr < 4; ++rr) {
            int r = r0 + wrow + fi * 16 + lq * 4 + rr;
            #pragma unroll
            for (int fj = 0; fj < 2; ++fj) {
                int h = h0 + wcol + fj * 16 + lr;
                xh[(size_t)r * H_ + h] = acc[fi][fj][rr] + bias[o * H_ + h];
            }
        }
}

// ---------------- A2a: inv-freq table (fp64) ----------------
__global__ void init_invf(double* __restrict__ invf) {
    int j = threadIdx.x;
    if (j < HALF_) invf[j] = exp2(-20.0 * (double)j / 384.0);
}

// ---------------- A2b: RoPE cos/sin tables (f32, separate arrays) ----------------
__global__ void rope_table(const int* __restrict__ sp,
                           const double* __restrict__ invf,
                           float* __restrict__ cosb, float* __restrict__ sinb) {
    int e = blockIdx.x * blockDim.x + threadIdx.x;  // 1024*384
    if (e >= B_ * 4 * P_ * HALF_) return;
    int j = e % HALF_;
    int r = e / HALF_;
    int s = sp[r];
    const double TWO_PI = 6.283185307179586476925286766559;
    double ang = (double)s * invf[j];
    double k = rint(ang * (1.0 / TWO_PI));
    float fr = (float)(ang - k * TWO_PI);
    float sv, cv;
    __sincosf(fr, &sv, &cv);
    cosb[e] = cv;
    sinb[e] = sv;
}

// ---------------- B: junction GEMM via bf16 MFMA ----------------
// block = one (b,sign,t), 512 threads = 8 waves, each 64x32 of 128x128 out.
// K=768 as 12 chunks of 64; f32 inputs, pk-f32 rope math, double-buffered
// swizzled bf16 LDS tiles, 1 barrier/chunk.
__global__ __launch_bounds__(512, 4) void junction_mfma(
    const float* __restrict__ xh,
    const float* __restrict__ cosb, const float* __restrict__ sinb,
    const float* __restrict__ rpd, const float* __restrict__ rpa,
    const float* __restrict__ rnd, const float* __restrict__ rna,
    const int* __restrict__ org, const int* __restrict__ sp,
    unsigned short* __restrict__ w1) {
    __shared__ __align__(16) unsigned short smem[4 * P_ * 64];  // 64KB: [buf][D|A][128*64]
    __shared__ int vD[P_], vA[P_];

    // bijective XCD swizzle (nwg = 1468, nwg%8 = 4)
    int nwg = gridDim.x;
    int orig = blockIdx.x;
    int xcd = orig & 7;
    int q = nwg >> 3, r8 = nwg & 7;
    int blk = (xcd < r8 ? xcd * (q + 1) : r8 * (q + 1) + (xcd - r8) * q) + (orig >> 3);

    int t = blk % T_;
    int sign = (blk / T_) & 1;
    int b = blk / (2 * T_);
    int o = org[b];
    int gd = sign * 2, ga = sign * 2 + 1;
    const float* pd = sign ? rnd : rpd;
    const float* pa = sign ? rna : rpa;
    int tid = threadIdx.x;

    const float* sc_d = pd + ((size_t)(o * 2 + 0) * T_ + t) * H_;
    const float* of_d = pd + ((size_t)(o * 2 + 1) * T_ + t) * H_;
    const float* sc_a = pa + ((size_t)(o * 2 + 0) * T_ + t) * H_;
    const float* of_a = pa + ((size_t)(o * 2 + 1) * T_ + t) * H_;

    if (tid < P_) {
        vD[tid] = sp[(b * 4 + gd) * P_ + tid] >= 0;
        vA[tid] = sp[(b * 4 + ga) * P_ + tid] >= 0;
    }
    const float* xd = xh + ((size_t)(b * 4 + gd) * P_) * H_;
    const float* xa = xh + ((size_t)(b * 4 + ga) * P_) * H_;
    const float* cd = cosb + ((size_t)(b * 4 + gd) * P_) * HALF_;
    const float* sd = sinb + ((size_t)(b * 4 + gd) * P_) * HALF_;
    const float* ca = cosb + ((size_t)(b * 4 + ga) * P_) * HALF_;
    const float* sa = sinb + ((size_t)(b * 4 + ga) * P_) * HALF_;

    int lane = tid & 63, wid = tid >> 6;
    int wrow = (wid >> 2) * 64, wcol = (wid & 3) * 32;
    int lr = lane & 15, lq = lane >> 4;
    int gr0 = (lq ^ (lr & 7)) * 8;

    f32x4 acc[4][2];
    #pragma unroll
    for (int i = 0; i < 4; ++i)
        #pragma unroll
        for (int j = 0; j < 2; ++j) acc[i][j] = (f32x4){0.f, 0.f, 0.f, 0.f};

    int jp = tid & 15;        // j-pair pair {2jp,2jp+1} within chunk
    int prow = tid >> 4;      // 0..31; p = pass*32 + prow, 4 passes

    for (int ch = 0; ch < 12; ++ch) {
        int jb = ch * 32 + 2 * jp;
        unsigned short* tDc = smem + (ch & 1) * 16384;
        unsigned short* tAc = tDc + 8192;

        // ---- donor side ----
        {
            f32x2 X1[4], X2[4], Cc[4], Ss[4];
            #pragma unroll
            for (int ps = 0; ps < 4; ++ps) {
                int p = ps * 32 + prow;
                X1[ps] = *(const f32x2*)(xd + p * H_ + jb);
                X2[ps] = *(const f32x2*)(xd + p * H_ + jb + HALF_);
                Cc[ps] = *(const f32x2*)(cd + p * HALF_ + jb);
                Ss[ps] = *(const f32x2*)(sd + p * HALF_ + jb);
            }
            f32x2 s1 = *(const f32x2*)(sc_d + jb);
            f32x2 o1 = *(const f32x2*)(of_d + jb);
            f32x2 s2 = *(const f32x2*)(sc_d + jb + HALF_);
            f32x2 o2 = *(const f32x2*)(of_d + jb + HALF_);
            #pragma unroll
            for (int ps = 0; ps < 4; ++ps) {
                int p = ps * 32 + prow;
                int sw = p * 64 + (((jp >> 1) ^ (p & 7)) << 3) + ((jp & 1) << 2);
                f32x2 u1 = __builtin_elementwise_fma(s1, X1[ps], o1);
                f32x2 u2 = __builtin_elementwise_fma(s2, X2[ps], o2);
                f32x2 t1 = u2 * Ss[ps];
                f32x2 r1 = __builtin_elementwise_fma(u1, Cc[ps], -t1);
                f32x2 t2 = u2 * Cc[ps];
                f32x2 r2 = __builtin_elementwise_fma(u1, Ss[ps], t2);
                uint2 wv;
                wv.x = packbf2(r1.x, r2.x);
                wv.y = packbf2(r1.y, r2.y);
                *(uint2*)&tDc[sw] = wv;
            }
        }
        // ---- acceptor side ----
        {
            f32x2 X1[4], X2[4], Cc[4], Ss[4];
            #pragma unroll
            for (int ps = 0; ps < 4; ++ps) {
                int p = ps * 32 + prow;
                X1[ps] = *(const f32x2*)(xa + p * H_ + jb);
                X2[ps] = *(const f32x2*)(xa + p * H_ + jb + HALF_);
                Cc[ps] = *(const f32x2*)(ca + p * HALF_ + jb);
                Ss[ps] = *(const f32x2*)(sa + p * HALF_ + jb);
            }
            f32x2 s1 = *(const f32x2*)(sc_a + jb);
            f32x2 o1 = *(const f32x2*)(of_a + jb);
            f32x2 s2 = *(const f32x2*)(sc_a + jb + HALF_);
            f32x2 o2 = *(const f32x2*)(of_a + jb + HALF_);
            #pragma unroll
            for (int ps = 0; ps < 4; ++ps) {
                int p = ps * 32 + prow;
                int sw = p * 64 + (((jp >> 1) ^ (p & 7)) << 3) + ((jp & 1) << 2);
                f32x2 u1 = __builtin_elementwise_fma(s1, X1[ps], o1);
                f32x2 u2 = __builtin_elementwise_fma(s2, X2[ps], o2);
                f32x2 t1 = u2 * Ss[ps];
                f32x2 r1 = __builtin_elementwise_fma(u1, Cc[ps], -t1);
                f32x2 t2 = u2 * Cc[ps];
                f32x2 r2 = __builtin_elementwise_fma(u1, Ss[ps], t2);
                uint2 wv;
                wv.x = packbf2(r1.x, r2.x);
                wv.y = packbf2(r1.y, r2.y);
                *(uint2*)&tAc[sw] = wv;
            }
        }
        __syncthreads();   // tiles[buf] built; prev chunk's reads (other buf) done earlier

        __builtin_amdgcn_s_setprio(1);
        #pragma unroll
        for (int kk = 0; kk < 64; kk += 32) {
            short8 af[4], bf2[2];
            #pragma unroll
            for (int fi = 0; fi < 4; ++fi)
                af[fi] = *(const short8*)&tDc[(wrow + fi * 16 + lr) * 64 + (gr0 ^ kk)];
            #pragma unroll
            for (int fj = 0; fj < 2; ++fj)
                bf2[fj] = *(const short8*)&tAc[(wcol + fj * 16 + lr) * 64 + (gr0 ^ kk)];
            #pragma unroll
            for (int fi = 0; fi < 4; ++fi)
                #pragma unroll
                for (int fj = 0; fj < 2; ++fj)
                    acc[fi][fj] = __builtin_amdgcn_mfma_f32_16x16x32_bf16(
                        af[fi], bf2[fj], acc[fi][fj], 0, 0, 0);
        }
        __builtin_amdgcn_s_setprio(0);
    }

    // ---- epilogue: softplus+mask -> bf16 LDS stage (buf0 area) -> coalesced copy ----
    unsigned short* stg = smem;    // 32KB region; last chunk read buf1 -> disjoint
    #pragma unroll
    for (int fi = 0; fi < 4; ++fi) {
        #pragma unroll
        for (int rr = 0; rr < 4; ++rr) {
            int d = wrow + fi * 16 + lq * 4 + rr;
            int vd = vD[d];
            #pragma unroll
            for (int fj = 0; fj < 2; ++fj) {
                int a = wcol + fj * 16 + lr;
                float x = acc[fi][fj][rr];
                float v = 0.0f;
                if (vd && vA[a]) v = (x > 15.0f) ? x : log1pf(__expf(x));
                stg[d * P_ + a] = packbf1(v);
            }
        }
    }
    __syncthreads();
    const uint4* src4 = (const uint4*)stg;                        // 2048 uint4
    uint4* dst4 = (uint4*)(w1 + ((size_t)((b * 2 + sign) * T_ + t) * P_) * P_);
    for (int i = tid; i < 2048; i += 512) dst4[i] = src4[i];
}

// ---------------- C: transpose bf16 [b][sign][t][d][a] -> f32 [b][d][a][sign*T+t] ----------------
__global__ __launch_bounds__(256) void transpose_out(const __hip_bfloat16* __restrict__ w1,
                                                     float* __restrict__ pred) {
    __shared__ float tile[64 * 129];
    int blk = blockIdx.x;            // bs*128*6 + d*6 + tt   (3072 blocks)
    int tt = blk % 6;
    int d = (blk / 6) % P_;
    int bs = blk / (6 * P_);         // b*2+sign
    int b = bs >> 1, sign = bs & 1;
    int t0 = tt * 64;
    int tcnt = min(64, T_ - t0);
    int tid = threadIdx.x;

    const __hip_bfloat16* src = w1 + (size_t)bs * T_ * P_ * P_ + (size_t)d * P_;
    for (int e = tid; e < tcnt * P_; e += 256) {
        int i = e >> 7, a = e & 127;
        tile[i * 129 + a] = __bfloat162float(src[(size_t)(t0 + i) * P_ * P_ + a]);
    }
    __syncthreads();
    float* dst = pred + ((size_t)(b * P_ + d) * P_) * TT_ + sign * T_ + t0;
    for (int e = tid; e < P_ * 64; e += 256) {
        int a = e >> 6, ii = e & 63;
        if (ii < tcnt) dst[(size_t)a * TT_ + ii] = tile[ii * 129 + a];
    }
}

// ---------------- D: mask fill ----------------
__global__ void mask_fill(const int* __restrict__ sp, float* __restrict__ mask) {
    int blk = blockIdx.x;            // (b*128+d)*128+a   (32768 blocks)
    int a = blk & 127;
    int d = (blk >> 7) & 127;
    int b = blk >> 14;
    bool vp = (sp[(b * 4 + 0) * P_ + d] >= 0) && (sp[(b * 4 + 1) * P_ + a] >= 0);
    bool vn = (sp[(b * 4 + 2) * P_ + d] >= 0) && (sp[(b * 4 + 3) * P_ + a] >= 0);
    float* dst = mask + (size_t)blk * TT_;
    for (int st = threadIdx.x; st < TT_; st += blockDim.x)
        dst[st] = (st < T_ ? vp : vn) ? 1.0f : 0.0f;
}

extern "C" void kernel_launch(void* const* d_in, const int* in_sizes, int n_in,
                              void* d_out, int out_size, void* d_ws, size_t ws_size,
                              hipStream_t stream) {
    const float* emb  = (const float*)d_in[0];
    const float* w    = (const float*)d_in[1];
    const float* bias = (const float*)d_in[2];
    const float* rpd  = (const float*)d_in[3];
    const float* rpa  = (const float*)d_in[4];
    const float* rnd  = (const float*)d_in[5];
    const float* rna  = (const float*)d_in[6];
    const int*   org  = (const int*)d_in[7];
    const int*   sp   = (const int*)d_in[8];

    float* out = (float*)d_out;
    float* ws  = (float*)d_ws;
    float* xh   = ws + XH_OFF;
    float* cosb = ws + COS_OFF;
    float* sinb = ws + SIN_OFF;
    double* invf = (double*)(ws + INVF_OFF);
    unsigned short* xcb = (unsigned short*)(ws + XCB_OFF);
    float* pred  = out;
    float* maskp = out + PRED_ELEMS;
    unsigned short* w1 = (unsigned short*)maskp;   // bf16 staging in mask half

    init_invf<<<1, 384, 0, stream>>>(invf);
    gather_cols<<<1024, 256, 0, stream>>>(emb, sp, xcb);
    rope_table<<<1536, 256, 0, stream>>>(sp, invf, cosb, sinb);
    dim3 gl(8, 12);
    logits_mfma<<<gl, 256, 0, stream>>>(xcb, w, bias, org, xh);
    junction_mfma<<<2 * 2 * T_, 512, 0, stream>>>(xh, cosb, sinb, rpd, rpa, rnd, rna, org, sp, w1);
    transpose_out<<<2 * 2 * P_ * 6, 256, 0, stream>>>((const __hip_bfloat16*)w1, pred);
    mask_fill<<<32768, 256, 0, stream>>>(sp, maskp);
}